// Round 14
// baseline (258.242 us; speedup 1.0000x reference)
//
#include <hip/hip_runtime.h>

using u16 = unsigned short;
typedef __attribute__((ext_vector_type(8))) __bf16 bf16x8;
typedef __attribute__((ext_vector_type(4))) float f32x4;
typedef __attribute__((ext_vector_type(16))) float f32x16;
typedef __attribute__((ext_vector_type(4))) unsigned int u32x4;
typedef __attribute__((ext_vector_type(2))) unsigned int u32x2;

__device__ inline u16 f2bf(float f) {
    unsigned u = __float_as_uint(f);
    u += 0x7FFFu + ((u >> 16) & 1u);   // RNE
    return (u16)(u >> 16);
}
__device__ inline unsigned pack2(float a, float b) {
    return (unsigned)f2bf(a) | ((unsigned)f2bf(b) << 16);
}
__device__ inline bf16x8 as_bf16x8(u32x4 v) {
    union { u32x4 u; bf16x8 b; } x; x.u = v; return x.b;
}
__device__ inline unsigned cvtpk(float lo, float hi) {
    unsigned w;
    asm("v_cvt_pk_bf16_f32 %0, %1, %2" : "=v"(w) : "v"(lo), "v"(hi));
    return w;
}
__device__ inline void gload_lds16(const void* g, void* l) {
    __builtin_amdgcn_global_load_lds(
        (const __attribute__((address_space(1))) void*)g,
        (__attribute__((address_space(3))) void*)l, 16, 0, 0);
}
// Ring-buffer barrier with airtight ordering (rule #18 fix).
__device__ inline void ring_barrier() {
    __builtin_amdgcn_sched_barrier(0);
    asm volatile("s_waitcnt lgkmcnt(0)" ::: "memory");
    __builtin_amdgcn_sched_barrier(0);
    __builtin_amdgcn_s_barrier();
    __builtin_amdgcn_sched_barrier(0);
}

// ---------------- elementwise cast fp32 -> bf16 (x) ------------------------
__global__ __launch_bounds__(256) void xcast(const float* __restrict__ in,
                                             u16* __restrict__ out) {
    const size_t i = ((size_t)blockIdx.x * 256 + threadIdx.x) * 8;
    f32x4 a = *(const f32x4*)(in + i);
    f32x4 b = *(const f32x4*)(in + i + 4);
    u32x4 w;
    w[0] = pack2(a[0], a[1]); w[1] = pack2(a[2], a[3]);
    w[2] = pack2(b[0], b[1]); w[3] = pack2(b[2], b[3]);
    *(u32x4*)(out + i) = w;
}

// ---------------- transpose + cast fp32 -> bf16 (for W^T) ----------------
__global__ __launch_bounds__(256) void tcast_f32(const float* __restrict__ in,
                                                 u16* __restrict__ out,
                                                 int R, int C) {
    __shared__ float tile[64][65];
    const int r0 = blockIdx.x * 64, c0 = blockIdx.y * 64;
    const int t = threadIdx.x;
    {
        const int r = t >> 2, cq = (t & 3) * 16;
        const float* src = in + (size_t)(r0 + r) * C + c0 + cq;
#pragma unroll
        for (int j = 0; j < 4; ++j) {
            f32x4 v = *(const f32x4*)(src + j * 4);
#pragma unroll
            for (int e = 0; e < 4; ++e) tile[r][cq + j * 4 + e] = v[e];
        }
    }
    __syncthreads();
    {
        const int c = t >> 2, rq = (t & 3) * 16;
        u32x4 w0, w1;
#pragma unroll
        for (int j = 0; j < 4; ++j) {
            w0[j] = pack2(tile[rq + 2 * j][c], tile[rq + 2 * j + 1][c]);
            w1[j] = pack2(tile[rq + 8 + 2 * j][c], tile[rq + 8 + 2 * j + 1][c]);
        }
        u16* dst = out + (size_t)(c0 + c) * R + r0 + rq;
        *(u32x4*)dst = w0;
        *(u32x4*)(dst + 8) = w1;
    }
}

// ---------------- GEMM: A [M][K] bf16 x Bt [N][K] bf16 + bias --------------
// 128x128 tile, BK=32, 256 thr. Depth-3 LDS ring via global_load_lds,
// counted vmcnt + hardened ring_barrier per K-step. (Unchanged from R13.)
template <int EPI>
__global__ __launch_bounds__(256) void gemm_kernel(const u16* __restrict__ A,
                                                   const u16* __restrict__ Bt,
                                                   const float* __restrict__ bias,
                                                   void* __restrict__ outp,
                                                   u16* __restrict__ vtp,
                                                   const int M, const int N, const int K) {
    __shared__ char lds[49152];            // 3 bufs x (A 8KB | B 8KB)
    const int t = threadIdx.x;
    const int l = t & 63, wid = t >> 6;
    const int wr = wid >> 1, wc = wid & 1;
    const int g = l >> 4, lr = l & 15;
    const int m0 = blockIdx.x * 128, n0 = blockIdx.y * 128;

    f32x4 acc[4][4];
#pragma unroll
    for (int i = 0; i < 4; ++i)
#pragma unroll
        for (int j = 0; j < 4; ++j)
#pragma unroll
            for (int e = 0; e < 4; ++e) acc[i][j][e] = 0.f;

    const size_t Kb2 = (size_t)K * 2;
    const size_t rowbA = (size_t)(m0 + wid * 16 + (l >> 2)) * Kb2 + (l & 3) * 16;
    const size_t rowbB = (size_t)(n0 + wid * 16 + (l >> 2)) * Kb2 + (l & 3) * 16;
    const int kn = K >> 5;

    auto STAGE = [&](int kk) {
        char* buf = lds + (kk % 3) * 16384;
        const size_t kb = (size_t)kk * 64;
#pragma unroll
        for (int j = 0; j < 2; ++j) {
            gload_lds16((const char*)A + rowbA + j * 64 * Kb2 + kb,
                        buf + j * 4096 + wid * 1024);
            gload_lds16((const char*)Bt + rowbB + j * 64 * Kb2 + kb,
                        buf + 8192 + j * 4096 + wid * 1024);
        }
    };

    STAGE(0); STAGE(1);
#pragma unroll 1
    for (int kk = 0; kk < kn; ++kk) {
        if (kk + 1 < kn) asm volatile("s_waitcnt vmcnt(4)" ::: "memory");
        else             asm volatile("s_waitcnt vmcnt(0)" ::: "memory");
        ring_barrier();
        if (kk + 2 < kn) STAGE(kk + 2);
        const char* As = lds + (kk % 3) * 16384;
        const char* Bs = As + 8192;
        bf16x8 a[4], b[4];
#pragma unroll
        for (int m = 0; m < 4; ++m) {
            const int row = wr * 64 + m * 16 + lr;
            a[m] = as_bf16x8(*(const u32x4*)(As + row * 64 + g * 16));
        }
#pragma unroll
        for (int n = 0; n < 4; ++n) {
            const int row = wc * 64 + n * 16 + lr;
            b[n] = as_bf16x8(*(const u32x4*)(Bs + row * 64 + g * 16));
        }
        __builtin_amdgcn_s_setprio(1);
#pragma unroll
        for (int m = 0; m < 4; ++m)
#pragma unroll
            for (int n = 0; n < 4; ++n)
                acc[m][n] = __builtin_amdgcn_mfma_f32_16x16x32_bf16(a[m], b[n], acc[m][n], 0, 0, 0);
        __builtin_amdgcn_s_setprio(0);
    }

    // Q pre-scale: uniform per block (n0 is a multiple of 128; 128 | 1024)
    const float qsc = (EPI == 0 && n0 < 1024) ? 0.18033688f : 1.0f;
#pragma unroll
    for (int m = 0; m < 4; ++m) {
#pragma unroll
        for (int n = 0; n < 4; ++n) {
            const int colg = n0 + wc * 64 + n * 16 + lr;
            const float bv = bias[colg];
            if constexpr (EPI == 0) {
                const int sec = colg >> 10, c = colg & 1023;
                const int hh = c >> 6, dd = c & 63;
                if (sec == 2) {
                    // V -> Vt [BH][64][T]: 4 consecutive t's, one 8B store
                    const int rowg0 = m0 + wr * 64 + m * 16 + g * 4;
                    const int bb = rowg0 >> 11, tt = rowg0 & 2047;
                    u16 pk[4];
#pragma unroll
                    for (int r = 0; r < 4; ++r)
                        pk[r] = f2bf(acc[m][n][r] + bv);
                    u16* dst = vtp + (((size_t)(bb * 16 + hh) * 64 + dd) << 11) + tt;
                    unsigned w0 = (unsigned)pk[0] | ((unsigned)pk[1] << 16);
                    unsigned w1 = (unsigned)pk[2] | ((unsigned)pk[3] << 16);
                    u32x2 wv; wv[0] = w0; wv[1] = w1;
                    *(u32x2*)dst = wv;
                } else {
#pragma unroll
                    for (int r = 0; r < 4; ++r) {
                        const int rowg = m0 + wr * 64 + m * 16 + g * 4 + r;
                        const float v = (acc[m][n][r] + bv) * qsc;
                        const int bb = rowg >> 11, tt = rowg & 2047;
                        u16* dst = (u16*)outp;
                        dst[(size_t)sec * 8388608u +
                            (((size_t)(bb * 16 + hh) * 2048 + tt) << 6) + dd] = f2bf(v);
                    }
                }
            } else {
#pragma unroll
                for (int r = 0; r < 4; ++r) {
                    const int rowg = m0 + wr * 64 + m * 16 + g * 4 + r;
                    ((float*)outp)[(size_t)rowg * N + colg] = acc[m][n][r] + bv;
                }
            }
        }
    }
}

// ---------------- fused causal flash attention, R14 ------------------------
// BARRIER-FREE: no LDS, no staging, no s_barrier, no waitcnt asm. K/V MFMA
// fragments read directly from global (L2-resident: XCD affinity puts this
// XCD's 8 bh x 512KB = 4MB of K/V in its own L2). Waves fully independent;
// each wave loops exactly its own ntw tiles.
// grid (16,BH)=1024 blocks, LPT p=15-(id>>6), bh=id&63 (XCD affinity).
// STATIC softmax (Q pre-scaled to log2 units), lane-local lacc.
__global__ __launch_bounds__(256) void attn_kernel(const u16* __restrict__ Q,
                                                   const u16* __restrict__ K,
                                                   const u16* __restrict__ Vt,
                                                   u16* __restrict__ Y) {
    const int t = threadIdx.x;
    const int l = t & 63, w = t >> 6;  // 4 waves
    const int q = l & 31, hi = l >> 5;
    const int id = (int)blockIdx.y * 16 + (int)blockIdx.x;   // nwg = 1024
    const int p = 15 - (id >> 6);      // heavy-first LPT
    const int bh = id & 63;            // XCD affinity: bh%8 == id%8
    const u16* Kb = K + (size_t)bh * 131072;
    const u16* Vb = Vt + (size_t)bh * 131072;
    const u16* Qb = Q + (size_t)bh * 131072;
    const int bb = bh >> 4, hh = bh & 15;

    const int q0w = p * 128 + w * 32;
    const int qg = q0w + q;
    const int ntw = ((q0w + 31) >> 6) + 1;    // this wave's tile count

    bf16x8 qf[4];
#pragma unroll
    for (int ks = 0; ks < 4; ++ks)
        qf[ks] = as_bf16x8(*(const u32x4*)(Qb + (size_t)(q0w + q) * 64 + ks * 16 + hi * 8));

    f32x16 o0, o1;
#pragma unroll
    for (int r = 0; r < 16; ++r) { o0[r] = 0.f; o1[r] = 0.f; }
    float lacc = 0.f;                  // lane-local unnormalized partial sum

#pragma unroll 1
    for (int it = 0; it < ntw; ++it) {
        const int kv0 = it << 6;
        // ---- V frags straight from global Vt (issued early; L2-resident) --
        u32x4 vf[8];
#pragma unroll
        for (int kvb = 0; kvb < 2; ++kvb)
#pragma unroll
            for (int s = 0; s < 2; ++s)
#pragma unroll
                for (int db = 0; db < 2; ++db)
                    vf[kvb * 4 + s * 2 + db] = *(const u32x4*)(
                        Vb + (size_t)(db * 32 + q) * 2048 + kv0 + kvb * 32 + s * 16 + hi * 8);
        // ---- QK^T (swapped) straight from global K; Q pre-scaled ----
        f32x16 s0, s1;
#pragma unroll
        for (int r = 0; r < 16; ++r) { s0[r] = 0.f; s1[r] = 0.f; }
        __builtin_amdgcn_s_setprio(1);
#pragma unroll
        for (int ks = 0; ks < 4; ++ks) {
            bf16x8 kf0 = as_bf16x8(*(const u32x4*)(
                Kb + (size_t)(kv0 + q) * 64 + ks * 16 + hi * 8));
            s0 = __builtin_amdgcn_mfma_f32_32x32x16_bf16(kf0, qf[ks], s0, 0, 0, 0);
            bf16x8 kf1 = as_bf16x8(*(const u32x4*)(
                Kb + (size_t)(kv0 + 32 + q) * 64 + ks * 16 + hi * 8));
            s1 = __builtin_amdgcn_mfma_f32_32x32x16_bf16(kf1, qf[ks], s1, 0, 0, 0);
        }
        __builtin_amdgcn_s_setprio(0);
        // ---- causal mask (near-diagonal tiles only) ----
        if (kv0 + 63 > q0w) {
#pragma unroll
            for (int r = 0; r < 16; ++r) {
                const int roff = (r & 3) + 8 * (r >> 2) + hi * 4;
                if (kv0 + roff > qg) s0[r] = -1.0e30f;
                if (kv0 + 32 + roff > qg) s1[r] = -1.0e30f;
            }
        }
        // ---- static softmax: p = exp2(s); lane-local accumulate ----
        float sm[8];
#pragma unroll
        for (int j = 0; j < 8; ++j) {
            s0[2 * j]     = exp2f(s0[2 * j]);
            s0[2 * j + 1] = exp2f(s0[2 * j + 1]);
            s1[2 * j]     = exp2f(s1[2 * j]);
            s1[2 * j + 1] = exp2f(s1[2 * j + 1]);
            sm[j] = (s0[2 * j] + s0[2 * j + 1]) + (s1[2 * j] + s1[2 * j + 1]);
        }
        lacc += ((sm[0] + sm[1]) + (sm[2] + sm[3])) +
                ((sm[4] + sm[5]) + (sm[6] + sm[7]));
        // ---- P -> A-frags (cvt_pk + permlane32_swap) + PV ----
#pragma unroll
        for (int kvb = 0; kvb < 2; ++kvb) {
            unsigned wd[8];
#pragma unroll
            for (int j = 0; j < 8; ++j) {
                const float plo = kvb ? s1[2 * j] : s0[2 * j];
                const float phi = kvb ? s1[2 * j + 1] : s0[2 * j + 1];
                wd[j] = cvtpk(plo, phi);
            }
            u32x2 r0 = __builtin_amdgcn_permlane32_swap(wd[0], wd[2], false, false);
            u32x2 r1 = __builtin_amdgcn_permlane32_swap(wd[1], wd[3], false, false);
            u32x2 r2 = __builtin_amdgcn_permlane32_swap(wd[4], wd[6], false, false);
            u32x2 r3 = __builtin_amdgcn_permlane32_swap(wd[5], wd[7], false, false);
            u32x4 fa, fb;
            fa[0] = r0[0]; fa[1] = r1[0]; fa[2] = r0[1]; fa[3] = r1[1];
            fb[0] = r2[0]; fb[1] = r3[0]; fb[2] = r2[1]; fb[3] = r3[1];
            const bf16x8 pa = as_bf16x8(fa), pb = as_bf16x8(fb);
            __builtin_amdgcn_s_setprio(1);
            o0 = __builtin_amdgcn_mfma_f32_32x32x16_bf16(pa, as_bf16x8(vf[kvb * 4 + 0]), o0, 0, 0, 0);
            o1 = __builtin_amdgcn_mfma_f32_32x32x16_bf16(pa, as_bf16x8(vf[kvb * 4 + 1]), o1, 0, 0, 0);
            o0 = __builtin_amdgcn_mfma_f32_32x32x16_bf16(pb, as_bf16x8(vf[kvb * 4 + 2]), o0, 0, 0, 0);
            o1 = __builtin_amdgcn_mfma_f32_32x32x16_bf16(pb, as_bf16x8(vf[kvb * 4 + 3]), o1, 0, 0, 0);
            __builtin_amdgcn_s_setprio(0);
        }
    }
    // ---- epilogue: single cross-half reduce for lsum, then normalize ----
    float lsum;
    {
        u32x2 rr = __builtin_amdgcn_permlane32_swap(
            __float_as_uint(lacc), __float_as_uint(lacc), false, false);
        lsum = lacc + __uint_as_float(hi ? rr[0] : rr[1]);
    }
    const float linv = 1.f / lsum;
#pragma unroll
    for (int r = 0; r < 16; ++r) {
        const int roff = (r & 3) + 8 * (r >> 2) + hi * 4;
        const float invq = __shfl(linv, roff);
        const size_t base = ((size_t)(bb * 2048 + q0w + roff)) * 1024 + hh * 64 + q;
        Y[base] = f2bf(o0[r] * invq);
        Y[base + 32] = f2bf(o1[r] * invq);
    }
}

// ---------------------------------------------------------------------------
extern "C" void kernel_launch(void* const* d_in, const int* in_sizes, int n_in,
                              void* d_out, int out_size, void* d_ws, size_t ws_size,
                              hipStream_t stream) {
    const float* x = (const float*)d_in[0];
    const float* Wqkv = (const float*)d_in[1];
    const float* bqkv = (const float*)d_in[2];
    const float* Wproj = (const float*)d_in[3];
    const float* bproj = (const float*)d_in[4];
    float* out = (float*)d_out;
    char* ws = (char*)d_ws;

    u16* Wtq = (u16*)(ws + 0);            // 3072x1024 bf16
    u16* Wtp = (u16*)(ws + 6291456);      // 1024x1024 bf16
    u16* Qb  = (u16*)(ws + 8388608);      // [B,H,T,64] bf16 x3 (Q,K,V slot)
    u16* Yb  = (u16*)(ws + 41943040);     // attn output (was V slot area)
    u16* Vtb = (u16*)(ws + 58720256);     // [B,H,64,T] bf16
    u16* Xb  = (u16*)(ws + 75497472);     // x in bf16

    xcast<<<4096, 256, 0, stream>>>(x, Xb);
    tcast_f32<<<dim3(16, 48), 256, 0, stream>>>(Wqkv, Wtq, 1024, 3072);
    tcast_f32<<<dim3(16, 16), 256, 0, stream>>>(Wproj, Wtp, 1024, 1024);
    gemm_kernel<0><<<dim3(64, 24), 256, 0, stream>>>(
        Xb, Wtq, bqkv, (void*)Qb, Vtb, 8192, 3072, 1024);
    attn_kernel<<<dim3(16, 64), 256, 0, stream>>>(
        Qb, Qb + 8388608, Vtb, Yb);
    gemm_kernel<1><<<dim3(64, 8), 256, 0, stream>>>(
        Yb, Wtp, bproj, (void*)out, nullptr, 8192, 1024, 1024);
}

// Round 15
// 182.924 us; speedup vs baseline: 1.4117x; 1.4117x over previous
//
#include <hip/hip_runtime.h>

using u16 = unsigned short;
typedef __attribute__((ext_vector_type(8))) __bf16 bf16x8;
typedef __attribute__((ext_vector_type(4))) float f32x4;
typedef __attribute__((ext_vector_type(16))) float f32x16;
typedef __attribute__((ext_vector_type(4))) unsigned int u32x4;
typedef __attribute__((ext_vector_type(2))) unsigned int u32x2;

__device__ inline u16 f2bf(float f) {
    unsigned u = __float_as_uint(f);
    u += 0x7FFFu + ((u >> 16) & 1u);   // RNE
    return (u16)(u >> 16);
}
__device__ inline unsigned pack2(float a, float b) {
    return (unsigned)f2bf(a) | ((unsigned)f2bf(b) << 16);
}
__device__ inline bf16x8 as_bf16x8(u32x4 v) {
    union { u32x4 u; bf16x8 b; } x; x.u = v; return x.b;
}
__device__ inline unsigned cvtpk(float lo, float hi) {
    unsigned w;
    asm("v_cvt_pk_bf16_f32 %0, %1, %2" : "=v"(w) : "v"(lo), "v"(hi));
    return w;
}
__device__ inline void gload_lds16(const void* g, void* l) {
    __builtin_amdgcn_global_load_lds(
        (const __attribute__((address_space(1))) void*)g,
        (__attribute__((address_space(3))) void*)l, 16, 0, 0);
}
// Ring-buffer barrier with airtight ordering (rule #18 fix).
__device__ inline void ring_barrier() {
    __builtin_amdgcn_sched_barrier(0);
    asm volatile("s_waitcnt lgkmcnt(0)" ::: "memory");
    __builtin_amdgcn_sched_barrier(0);
    __builtin_amdgcn_s_barrier();
    __builtin_amdgcn_sched_barrier(0);
}

// ---------------- elementwise cast fp32 -> bf16 (x) ------------------------
__global__ __launch_bounds__(256) void xcast(const float* __restrict__ in,
                                             u16* __restrict__ out) {
    const size_t i = ((size_t)blockIdx.x * 256 + threadIdx.x) * 8;
    f32x4 a = *(const f32x4*)(in + i);
    f32x4 b = *(const f32x4*)(in + i + 4);
    u32x4 w;
    w[0] = pack2(a[0], a[1]); w[1] = pack2(a[2], a[3]);
    w[2] = pack2(b[0], b[1]); w[3] = pack2(b[2], b[3]);
    *(u32x4*)(out + i) = w;
}

// ------- merged transpose+cast fp32 -> bf16 for BOTH weight matrices -------
// grid (16, 64): by<48 -> Wqkv (1024x3072), else Wproj (1024x1024).
__global__ __launch_bounds__(256) void tcast2(const float* __restrict__ Wqkv,
                                              const float* __restrict__ Wproj,
                                              u16* __restrict__ Wtq,
                                              u16* __restrict__ Wtp) {
    __shared__ float tile[64][65];
    const int by = blockIdx.y;
    const float* in;
    u16* out;
    int C, c0;
    if (by < 48) { in = Wqkv;  out = Wtq; C = 3072; c0 = by * 64; }
    else         { in = Wproj; out = Wtp; C = 1024; c0 = (by - 48) * 64; }
    const int R = 1024, r0 = blockIdx.x * 64;
    const int t = threadIdx.x;
    {
        const int r = t >> 2, cq = (t & 3) * 16;
        const float* src = in + (size_t)(r0 + r) * C + c0 + cq;
#pragma unroll
        for (int j = 0; j < 4; ++j) {
            f32x4 v = *(const f32x4*)(src + j * 4);
#pragma unroll
            for (int e = 0; e < 4; ++e) tile[r][cq + j * 4 + e] = v[e];
        }
    }
    __syncthreads();
    {
        const int c = t >> 2, rq = (t & 3) * 16;
        u32x4 w0, w1;
#pragma unroll
        for (int j = 0; j < 4; ++j) {
            w0[j] = pack2(tile[rq + 2 * j][c], tile[rq + 2 * j + 1][c]);
            w1[j] = pack2(tile[rq + 8 + 2 * j][c], tile[rq + 8 + 2 * j + 1][c]);
        }
        u16* dst = out + (size_t)(c0 + c) * R + r0 + rq;
        *(u32x4*)dst = w0;
        *(u32x4*)(dst + 8) = w1;
    }
}

// ---------------- GEMM: A [M][K] bf16 x Bt [N][K] bf16 + bias --------------
// 128x128 tile, BK=32, 256 thr. Depth-3 LDS ring via global_load_lds,
// counted vmcnt + hardened ring_barrier per K-step.
// EPI0: QKV routing; Q pre-scaled by 0.125*log2(e); V written directly
//       transposed to Vt [BH][64][T] (eliminates the tv_bf16 kernel).
// EPI1: fp32 store out[row*N+col].
template <int EPI>
__global__ __launch_bounds__(256) void gemm_kernel(const u16* __restrict__ A,
                                                   const u16* __restrict__ Bt,
                                                   const float* __restrict__ bias,
                                                   void* __restrict__ outp,
                                                   u16* __restrict__ vtp,
                                                   const int M, const int N, const int K) {
    __shared__ char lds[49152];            // 3 bufs x (A 8KB | B 8KB)
    const int t = threadIdx.x;
    const int l = t & 63, wid = t >> 6;
    const int wr = wid >> 1, wc = wid & 1;
    const int g = l >> 4, lr = l & 15;
    const int m0 = blockIdx.x * 128, n0 = blockIdx.y * 128;

    f32x4 acc[4][4];
#pragma unroll
    for (int i = 0; i < 4; ++i)
#pragma unroll
        for (int j = 0; j < 4; ++j)
#pragma unroll
            for (int e = 0; e < 4; ++e) acc[i][j][e] = 0.f;

    const size_t Kb2 = (size_t)K * 2;
    const size_t rowbA = (size_t)(m0 + wid * 16 + (l >> 2)) * Kb2 + (l & 3) * 16;
    const size_t rowbB = (size_t)(n0 + wid * 16 + (l >> 2)) * Kb2 + (l & 3) * 16;
    const int kn = K >> 5;

    auto STAGE = [&](int kk) {
        char* buf = lds + (kk % 3) * 16384;
        const size_t kb = (size_t)kk * 64;
#pragma unroll
        for (int j = 0; j < 2; ++j) {
            gload_lds16((const char*)A + rowbA + j * 64 * Kb2 + kb,
                        buf + j * 4096 + wid * 1024);
            gload_lds16((const char*)Bt + rowbB + j * 64 * Kb2 + kb,
                        buf + 8192 + j * 4096 + wid * 1024);
        }
    };

    STAGE(0); STAGE(1);
#pragma unroll 1
    for (int kk = 0; kk < kn; ++kk) {
        if (kk + 1 < kn) asm volatile("s_waitcnt vmcnt(4)" ::: "memory");
        else             asm volatile("s_waitcnt vmcnt(0)" ::: "memory");
        ring_barrier();
        if (kk + 2 < kn) STAGE(kk + 2);
        const char* As = lds + (kk % 3) * 16384;
        const char* Bs = As + 8192;
        bf16x8 a[4], b[4];
#pragma unroll
        for (int m = 0; m < 4; ++m) {
            const int row = wr * 64 + m * 16 + lr;
            a[m] = as_bf16x8(*(const u32x4*)(As + row * 64 + g * 16));
        }
#pragma unroll
        for (int n = 0; n < 4; ++n) {
            const int row = wc * 64 + n * 16 + lr;
            b[n] = as_bf16x8(*(const u32x4*)(Bs + row * 64 + g * 16));
        }
        __builtin_amdgcn_s_setprio(1);
#pragma unroll
        for (int m = 0; m < 4; ++m)
#pragma unroll
            for (int n = 0; n < 4; ++n)
                acc[m][n] = __builtin_amdgcn_mfma_f32_16x16x32_bf16(a[m], b[n], acc[m][n], 0, 0, 0);
        __builtin_amdgcn_s_setprio(0);
    }

    // Q pre-scale: uniform per block (n0 is a multiple of 128; 128 | 1024)
    const float qsc = (EPI == 0 && n0 < 1024) ? 0.18033688f : 1.0f;
#pragma unroll
    for (int m = 0; m < 4; ++m) {
#pragma unroll
        for (int n = 0; n < 4; ++n) {
            const int colg = n0 + wc * 64 + n * 16 + lr;
            const float bv = bias[colg];
            if constexpr (EPI == 0) {
                const int sec = colg >> 10, c = colg & 1023;
                const int hh = c >> 6, dd = c & 63;
                if (sec == 2) {
                    // V -> Vt [BH][64][T]: 4 consecutive t's, one 8B store
                    const int rowg0 = m0 + wr * 64 + m * 16 + g * 4;
                    const int bb = rowg0 >> 11, tt = rowg0 & 2047;
                    u16 pk[4];
#pragma unroll
                    for (int r = 0; r < 4; ++r)
                        pk[r] = f2bf(acc[m][n][r] + bv);
                    u16* dst = vtp + (((size_t)(bb * 16 + hh) * 64 + dd) << 11) + tt;
                    unsigned w0 = (unsigned)pk[0] | ((unsigned)pk[1] << 16);
                    unsigned w1 = (unsigned)pk[2] | ((unsigned)pk[3] << 16);
                    u32x2 wv; wv[0] = w0; wv[1] = w1;
                    *(u32x2*)dst = wv;
                } else {
#pragma unroll
                    for (int r = 0; r < 4; ++r) {
                        const int rowg = m0 + wr * 64 + m * 16 + g * 4 + r;
                        const float v = (acc[m][n][r] + bv) * qsc;
                        const int bb = rowg >> 11, tt = rowg & 2047;
                        u16* dst = (u16*)outp;
                        dst[(size_t)sec * 8388608u +
                            (((size_t)(bb * 16 + hh) * 2048 + tt) << 6) + dd] = f2bf(v);
                    }
                }
            } else {
#pragma unroll
                for (int r = 0; r < 4; ++r) {
                    const int rowg = m0 + wr * 64 + m * 16 + g * 4 + r;
                    ((float*)outp)[(size_t)rowg * N + colg] = acc[m][n][r] + bv;
                }
            }
        }
    }
}

// ---------------- fused causal flash attention (R12/R13 best) --------------
// grid (16,BH)=1024 blocks, LPT p=15-(id>>6), bh=id&63 (XCD affinity).
// Depth-2 LDS ring (32KB) via global_load_lds, counted staging, hardened
// ring_barrier. STATIC softmax (Q pre-scaled to log2 units), lane-local
// lacc, single cross-half permlane reduce in epilogue.
// NOTE (R14 lesson): the LDS staging is the latency-hiding vehicle, not a
// bandwidth dedup -- direct-L2 MFMA feeds are ~2x slower even when resident.
__global__ __launch_bounds__(256) void attn_kernel(const u16* __restrict__ Q,
                                                   const u16* __restrict__ K,
                                                   const u16* __restrict__ Vt,
                                                   u16* __restrict__ Y) {
    __shared__ char lds[32768];        // 2 bufs x (K 8KB | V 8KB)
    const int t = threadIdx.x;
    const int l = t & 63, w = t >> 6;  // 4 waves
    const int q = l & 31, hi = l >> 5;
    const int id = (int)blockIdx.y * 16 + (int)blockIdx.x;   // nwg = 1024
    const int p = 15 - (id >> 6);      // heavy-first LPT
    const int bh = id & 63;            // XCD affinity: bh%8 == id%8
    const char* Kby = (const char*)(K + (size_t)bh * 131072);
    const char* Vby = (const char*)(Vt + (size_t)bh * 131072);
    const u16* Qb = Q + (size_t)bh * 131072;
    const int bb = bh >> 4, hh = bh & 15;
    const unsigned ck = (unsigned)(((l & 7) ^ (l >> 3)) << 4);
    const unsigned rd_swz = (unsigned)((q & 7) << 4);

    const int q0w = p * 128 + w * 32;
    const int qg = q0w + q;
    const int NT = 2 * p + 2;                 // block tile count
    const int ntw = ((q0w + 31) >> 6) + 1;    // this wave's tile count

    bf16x8 qf[4];
#pragma unroll
    for (int ks = 0; ks < 4; ++ks)
        qf[ks] = as_bf16x8(*(const u32x4*)(Qb + (size_t)(q0w + q) * 64 + ks * 16 + hi * 8));

    f32x16 o0, o1;
#pragma unroll
    for (int r = 0; r < 16; ++r) { o0[r] = 0.f; o1[r] = 0.f; }
    float lacc = 0.f;                  // lane-local unnormalized partial sum

    auto STAGE = [&](int it) {
        const int kv0 = it << 6;
        char* base = lds + (it & 1) * 16384;
#pragma unroll
        for (int j = 0; j < 2; ++j) {
            const int r = w * 16 + j * 8 + (l >> 3);
            gload_lds16(Kby + (size_t)(kv0 + r) * 128 + ck,
                        base + w * 2048 + j * 1024);
            gload_lds16(Vby + (size_t)r * 4096 + (size_t)kv0 * 2 + ck,
                        base + 8192 + w * 2048 + j * 1024);
        }
    };

    STAGE(0);
#pragma unroll 1
    for (int it = 0; it < NT; ++it) {
        asm volatile("s_waitcnt vmcnt(0)" ::: "memory");   // stage(it) landed
        ring_barrier();                 // prev readers of buf[(it+1)&1] done
        if (it + 1 < NT) STAGE(it + 1);
        if (it < ntw) {
            const int kv0 = it << 6;
            const char* Kl = lds + (it & 1) * 16384;
            const char* Vl = Kl + 8192;
            // ---- V frags from LDS (swizzled), issued early ----
            u32x4 vf[8];
#pragma unroll
            for (int kvb = 0; kvb < 2; ++kvb)
#pragma unroll
                for (int s = 0; s < 2; ++s)
#pragma unroll
                    for (int db = 0; db < 2; ++db)
                        vf[kvb * 4 + s * 2 + db] = *(const u32x4*)(
                            Vl + (unsigned)((db * 32 + q) * 128) +
                            ((unsigned)(kvb * 64 + s * 32 + hi * 16) ^ rd_swz));
            // ---- QK^T (swapped) from LDS K; Q pre-scaled (log2 units) ----
            f32x16 s0, s1;
#pragma unroll
            for (int r = 0; r < 16; ++r) { s0[r] = 0.f; s1[r] = 0.f; }
            __builtin_amdgcn_s_setprio(1);
#pragma unroll
            for (int ks = 0; ks < 4; ++ks) {
                const unsigned co = (unsigned)(ks * 32 + hi * 16) ^ rd_swz;
                bf16x8 kf0 = as_bf16x8(*(const u32x4*)(Kl + (unsigned)(q * 128) + co));
                s0 = __builtin_amdgcn_mfma_f32_32x32x16_bf16(kf0, qf[ks], s0, 0, 0, 0);
                bf16x8 kf1 = as_bf16x8(*(const u32x4*)(Kl + (unsigned)((32 + q) * 128) + co));
                s1 = __builtin_amdgcn_mfma_f32_32x32x16_bf16(kf1, qf[ks], s1, 0, 0, 0);
            }
            __builtin_amdgcn_s_setprio(0);
            // ---- causal mask (near-diagonal tiles only) ----
            if (kv0 + 63 > q0w) {
#pragma unroll
                for (int r = 0; r < 16; ++r) {
                    const int roff = (r & 3) + 8 * (r >> 2) + hi * 4;
                    if (kv0 + roff > qg) s0[r] = -1.0e30f;
                    if (kv0 + 32 + roff > qg) s1[r] = -1.0e30f;
                }
            }
            // ---- static softmax: p = exp2(s); lane-local accumulate ----
            float sm[8];
#pragma unroll
            for (int j = 0; j < 8; ++j) {
                s0[2 * j]     = exp2f(s0[2 * j]);
                s0[2 * j + 1] = exp2f(s0[2 * j + 1]);
                s1[2 * j]     = exp2f(s1[2 * j]);
                s1[2 * j + 1] = exp2f(s1[2 * j + 1]);
                sm[j] = (s0[2 * j] + s0[2 * j + 1]) + (s1[2 * j] + s1[2 * j + 1]);
            }
            lacc += ((sm[0] + sm[1]) + (sm[2] + sm[3])) +
                    ((sm[4] + sm[5]) + (sm[6] + sm[7]));
            // ---- P -> A-frags (cvt_pk + permlane32_swap) + PV ----
#pragma unroll
            for (int kvb = 0; kvb < 2; ++kvb) {
                unsigned wd[8];
#pragma unroll
                for (int j = 0; j < 8; ++j) {
                    const float plo = kvb ? s1[2 * j] : s0[2 * j];
                    const float phi = kvb ? s1[2 * j + 1] : s0[2 * j + 1];
                    wd[j] = cvtpk(plo, phi);
                }
                u32x2 r0 = __builtin_amdgcn_permlane32_swap(wd[0], wd[2], false, false);
                u32x2 r1 = __builtin_amdgcn_permlane32_swap(wd[1], wd[3], false, false);
                u32x2 r2 = __builtin_amdgcn_permlane32_swap(wd[4], wd[6], false, false);
                u32x2 r3 = __builtin_amdgcn_permlane32_swap(wd[5], wd[7], false, false);
                u32x4 fa, fb;
                fa[0] = r0[0]; fa[1] = r1[0]; fa[2] = r0[1]; fa[3] = r1[1];
                fb[0] = r2[0]; fb[1] = r3[0]; fb[2] = r2[1]; fb[3] = r3[1];
                const bf16x8 pa = as_bf16x8(fa), pb = as_bf16x8(fb);
                __builtin_amdgcn_s_setprio(1);
                o0 = __builtin_amdgcn_mfma_f32_32x32x16_bf16(pa, as_bf16x8(vf[kvb * 4 + 0]), o0, 0, 0, 0);
                o1 = __builtin_amdgcn_mfma_f32_32x32x16_bf16(pa, as_bf16x8(vf[kvb * 4 + 1]), o1, 0, 0, 0);
                o0 = __builtin_amdgcn_mfma_f32_32x32x16_bf16(pb, as_bf16x8(vf[kvb * 4 + 2]), o0, 0, 0, 0);
                o1 = __builtin_amdgcn_mfma_f32_32x32x16_bf16(pb, as_bf16x8(vf[kvb * 4 + 3]), o1, 0, 0, 0);
                __builtin_amdgcn_s_setprio(0);
            }
        }
    }
    // ---- epilogue: single cross-half reduce for lsum, then normalize ----
    float lsum;
    {
        u32x2 rr = __builtin_amdgcn_permlane32_swap(
            __float_as_uint(lacc), __float_as_uint(lacc), false, false);
        lsum = lacc + __uint_as_float(hi ? rr[0] : rr[1]);
    }
    const float linv = 1.f / lsum;
#pragma unroll
    for (int r = 0; r < 16; ++r) {
        const int roff = (r & 3) + 8 * (r >> 2) + hi * 4;
        const float invq = __shfl(linv, roff);
        const size_t base = ((size_t)(bb * 2048 + q0w + roff)) * 1024 + hh * 64 + q;
        Y[base] = f2bf(o0[r] * invq);
        Y[base + 32] = f2bf(o1[r] * invq);
    }
}

// ---------------------------------------------------------------------------
extern "C" void kernel_launch(void* const* d_in, const int* in_sizes, int n_in,
                              void* d_out, int out_size, void* d_ws, size_t ws_size,
                              hipStream_t stream) {
    const float* x = (const float*)d_in[0];
    const float* Wqkv = (const float*)d_in[1];
    const float* bqkv = (const float*)d_in[2];
    const float* Wproj = (const float*)d_in[3];
    const float* bproj = (const float*)d_in[4];
    float* out = (float*)d_out;
    char* ws = (char*)d_ws;

    u16* Wtq = (u16*)(ws + 0);            // 3072x1024 bf16
    u16* Wtp = (u16*)(ws + 6291456);      // 1024x1024 bf16
    u16* Qb  = (u16*)(ws + 8388608);      // [B,H,T,64] bf16 x3 (Q,K,V slot)
    u16* Yb  = (u16*)(ws + 41943040);     // attn output
    u16* Vtb = (u16*)(ws + 58720256);     // [B,H,64,T] bf16
    u16* Xb  = (u16*)(ws + 75497472);     // x in bf16

    xcast<<<4096, 256, 0, stream>>>(x, Xb);
    tcast2<<<dim3(16, 64), 256, 0, stream>>>(Wqkv, Wproj, Wtq, Wtp);
    gemm_kernel<0><<<dim3(64, 24), 256, 0, stream>>>(
        Xb, Wtq, bqkv, (void*)Qb, Vtb, 8192, 3072, 1024);
    attn_kernel<<<dim3(16, 64), 256, 0, stream>>>(
        Qb, Qb + 8388608, Vtb, Yb);
    gemm_kernel<1><<<dim3(64, 8), 256, 0, stream>>>(
        Yb, Wtp, bproj, (void*)out, nullptr, 8192, 1024, 1024);
}

// Round 16
// 178.504 us; speedup vs baseline: 1.4467x; 1.0248x over previous
//
#include <hip/hip_runtime.h>

using u16 = unsigned short;
typedef __attribute__((ext_vector_type(8))) __bf16 bf16x8;
typedef __attribute__((ext_vector_type(4))) float f32x4;
typedef __attribute__((ext_vector_type(16))) float f32x16;
typedef __attribute__((ext_vector_type(4))) unsigned int u32x4;
typedef __attribute__((ext_vector_type(2))) unsigned int u32x2;

__device__ inline u16 f2bf(float f) {
    unsigned u = __float_as_uint(f);
    u += 0x7FFFu + ((u >> 16) & 1u);   // RNE
    return (u16)(u >> 16);
}
__device__ inline unsigned pack2(float a, float b) {
    return (unsigned)f2bf(a) | ((unsigned)f2bf(b) << 16);
}
__device__ inline bf16x8 as_bf16x8(u32x4 v) {
    union { u32x4 u; bf16x8 b; } x; x.u = v; return x.b;
}
__device__ inline unsigned cvtpk(float lo, float hi) {
    unsigned w;
    asm("v_cvt_pk_bf16_f32 %0, %1, %2" : "=v"(w) : "v"(lo), "v"(hi));
    return w;
}
__device__ inline void gload_lds16(const void* g, void* l) {
    __builtin_amdgcn_global_load_lds(
        (const __attribute__((address_space(1))) void*)g,
        (__attribute__((address_space(3))) void*)l, 16, 0, 0);
}
// Ring-buffer barrier with airtight ordering (rule #18 fix).
__device__ inline void ring_barrier() {
    __builtin_amdgcn_sched_barrier(0);
    asm volatile("s_waitcnt lgkmcnt(0)" ::: "memory");
    __builtin_amdgcn_sched_barrier(0);
    __builtin_amdgcn_s_barrier();
    __builtin_amdgcn_sched_barrier(0);
}

// ---------------- elementwise cast fp32 -> bf16 (x) ------------------------
__global__ __launch_bounds__(256) void xcast(const float* __restrict__ in,
                                             u16* __restrict__ out) {
    const size_t i = ((size_t)blockIdx.x * 256 + threadIdx.x) * 8;
    f32x4 a = *(const f32x4*)(in + i);
    f32x4 b = *(const f32x4*)(in + i + 4);
    u32x4 w;
    w[0] = pack2(a[0], a[1]); w[1] = pack2(a[2], a[3]);
    w[2] = pack2(b[0], b[1]); w[3] = pack2(b[2], b[3]);
    *(u32x4*)(out + i) = w;
}

// ------- merged transpose+cast fp32 -> bf16 for BOTH weight matrices -------
// grid (16, 64): by<48 -> Wqkv (1024x3072), else Wproj (1024x1024).
__global__ __launch_bounds__(256) void tcast2(const float* __restrict__ Wqkv,
                                              const float* __restrict__ Wproj,
                                              u16* __restrict__ Wtq,
                                              u16* __restrict__ Wtp) {
    __shared__ float tile[64][65];
    const int by = blockIdx.y;
    const float* in;
    u16* out;
    int C, c0;
    if (by < 48) { in = Wqkv;  out = Wtq; C = 3072; c0 = by * 64; }
    else         { in = Wproj; out = Wtp; C = 1024; c0 = (by - 48) * 64; }
    const int R = 1024, r0 = blockIdx.x * 64;
    const int t = threadIdx.x;
    {
        const int r = t >> 2, cq = (t & 3) * 16;
        const float* src = in + (size_t)(r0 + r) * C + c0 + cq;
#pragma unroll
        for (int j = 0; j < 4; ++j) {
            f32x4 v = *(const f32x4*)(src + j * 4);
#pragma unroll
            for (int e = 0; e < 4; ++e) tile[r][cq + j * 4 + e] = v[e];
        }
    }
    __syncthreads();
    {
        const int c = t >> 2, rq = (t & 3) * 16;
        u32x4 w0, w1;
#pragma unroll
        for (int j = 0; j < 4; ++j) {
            w0[j] = pack2(tile[rq + 2 * j][c], tile[rq + 2 * j + 1][c]);
            w1[j] = pack2(tile[rq + 8 + 2 * j][c], tile[rq + 8 + 2 * j + 1][c]);
        }
        u16* dst = out + (size_t)(c0 + c) * R + r0 + rq;
        *(u32x4*)dst = w0;
        *(u32x4*)(dst + 8) = w1;
    }
}

// ---------------- GEMM: A [M][K] bf16 x Bt [N][K] bf16 + bias --------------
// 128x128 tile, BK=32, 256 thr. Depth-3 LDS ring via global_load_lds,
// counted vmcnt + hardened ring_barrier per K-step.
// EPI0: QKV routing; Q pre-scaled by 0.125*log2(e); V written directly
//       transposed to Vt [BH][64][T].
// EPI1: fp32 store out[row*N+col].
template <int EPI>
__global__ __launch_bounds__(256) void gemm_kernel(const u16* __restrict__ A,
                                                   const u16* __restrict__ Bt,
                                                   const float* __restrict__ bias,
                                                   void* __restrict__ outp,
                                                   u16* __restrict__ vtp,
                                                   const int M, const int N, const int K) {
    __shared__ char lds[49152];            // 3 bufs x (A 8KB | B 8KB)
    const int t = threadIdx.x;
    const int l = t & 63, wid = t >> 6;
    const int wr = wid >> 1, wc = wid & 1;
    const int g = l >> 4, lr = l & 15;
    const int m0 = blockIdx.x * 128, n0 = blockIdx.y * 128;

    f32x4 acc[4][4];
#pragma unroll
    for (int i = 0; i < 4; ++i)
#pragma unroll
        for (int j = 0; j < 4; ++j)
#pragma unroll
            for (int e = 0; e < 4; ++e) acc[i][j][e] = 0.f;

    const size_t Kb2 = (size_t)K * 2;
    const size_t rowbA = (size_t)(m0 + wid * 16 + (l >> 2)) * Kb2 + (l & 3) * 16;
    const size_t rowbB = (size_t)(n0 + wid * 16 + (l >> 2)) * Kb2 + (l & 3) * 16;
    const int kn = K >> 5;

    auto STAGE = [&](int kk) {
        char* buf = lds + (kk % 3) * 16384;
        const size_t kb = (size_t)kk * 64;
#pragma unroll
        for (int j = 0; j < 2; ++j) {
            gload_lds16((const char*)A + rowbA + j * 64 * Kb2 + kb,
                        buf + j * 4096 + wid * 1024);
            gload_lds16((const char*)Bt + rowbB + j * 64 * Kb2 + kb,
                        buf + 8192 + j * 4096 + wid * 1024);
        }
    };

    STAGE(0); STAGE(1);
#pragma unroll 1
    for (int kk = 0; kk < kn; ++kk) {
        if (kk + 1 < kn) asm volatile("s_waitcnt vmcnt(4)" ::: "memory");
        else             asm volatile("s_waitcnt vmcnt(0)" ::: "memory");
        ring_barrier();
        if (kk + 2 < kn) STAGE(kk + 2);
        const char* As = lds + (kk % 3) * 16384;
        const char* Bs = As + 8192;
        bf16x8 a[4], b[4];
#pragma unroll
        for (int m = 0; m < 4; ++m) {
            const int row = wr * 64 + m * 16 + lr;
            a[m] = as_bf16x8(*(const u32x4*)(As + row * 64 + g * 16));
        }
#pragma unroll
        for (int n = 0; n < 4; ++n) {
            const int row = wc * 64 + n * 16 + lr;
            b[n] = as_bf16x8(*(const u32x4*)(Bs + row * 64 + g * 16));
        }
        __builtin_amdgcn_s_setprio(1);
#pragma unroll
        for (int m = 0; m < 4; ++m)
#pragma unroll
            for (int n = 0; n < 4; ++n)
                acc[m][n] = __builtin_amdgcn_mfma_f32_16x16x32_bf16(a[m], b[n], acc[m][n], 0, 0, 0);
        __builtin_amdgcn_s_setprio(0);
    }

    // Q pre-scale: uniform per block (n0 is a multiple of 128; 128 | 1024)
    const float qsc = (EPI == 0 && n0 < 1024) ? 0.18033688f : 1.0f;
#pragma unroll
    for (int m = 0; m < 4; ++m) {
#pragma unroll
        for (int n = 0; n < 4; ++n) {
            const int colg = n0 + wc * 64 + n * 16 + lr;
            const float bv = bias[colg];
            if constexpr (EPI == 0) {
                const int sec = colg >> 10, c = colg & 1023;
                const int hh = c >> 6, dd = c & 63;
                if (sec == 2) {
                    // V -> Vt [BH][64][T]: 4 consecutive t's, one 8B store
                    const int rowg0 = m0 + wr * 64 + m * 16 + g * 4;
                    const int bb = rowg0 >> 11, tt = rowg0 & 2047;
                    u16 pk[4];
#pragma unroll
                    for (int r = 0; r < 4; ++r)
                        pk[r] = f2bf(acc[m][n][r] + bv);
                    u16* dst = vtp + (((size_t)(bb * 16 + hh) * 64 + dd) << 11) + tt;
                    unsigned w0 = (unsigned)pk[0] | ((unsigned)pk[1] << 16);
                    unsigned w1 = (unsigned)pk[2] | ((unsigned)pk[3] << 16);
                    u32x2 wv; wv[0] = w0; wv[1] = w1;
                    *(u32x2*)dst = wv;
                } else {
#pragma unroll
                    for (int r = 0; r < 4; ++r) {
                        const int rowg = m0 + wr * 64 + m * 16 + g * 4 + r;
                        const float v = (acc[m][n][r] + bv) * qsc;
                        const int bb = rowg >> 11, tt = rowg & 2047;
                        u16* dst = (u16*)outp;
                        dst[(size_t)sec * 8388608u +
                            (((size_t)(bb * 16 + hh) * 2048 + tt) << 6) + dd] = f2bf(v);
                    }
                }
            } else {
#pragma unroll
                for (int r = 0; r < 4; ++r) {
                    const int rowg = m0 + wr * 64 + m * 16 + g * 4 + r;
                    ((float*)outp)[(size_t)rowg * N + colg] = acc[m][n][r] + bv;
                }
            }
        }
    }
}

// ---------------- fused causal flash attention, R16 ------------------------
// R12/R13 staged kernel with a CLASS-BALANCED p-permutation: with 4 blocks
// resident per CU and stride-256 round-robin dispatch, a CU hosts p-groups
// {g0, g0+4, g0+8, g0+12}. The permutation below makes every such class sum
// to 30 (i.e. 68 iters/CU, the global mean) while keeping heavy-first order
// within each class. bh = id&63 unchanged -> XCD affinity; map stays
// bijective over (p, bh).
__global__ __launch_bounds__(256) void attn_kernel(const u16* __restrict__ Q,
                                                   const u16* __restrict__ K,
                                                   const u16* __restrict__ Vt,
                                                   u16* __restrict__ Y) {
    __shared__ char lds[32768];        // 2 bufs x (K 8KB | V 8KB)
    const int t = threadIdx.x;
    const int l = t & 63, w = t >> 6;  // 4 waves
    const int q = l & 31, hi = l >> 5;
    const int id = (int)blockIdx.y * 16 + (int)blockIdx.x;   // nwg = 1024
    const int grp = id >> 6;           // p-group 0..15
    // packed nibble table: classes {15,8,6,1}{14,9,4,3}{13,10,5,2}{12,11,7,0}
    const int p = (int)((0x02317546BA98CDEFull >> (grp * 4)) & 15ull);
    const int bh = id & 63;            // XCD affinity: bh%8 == id%8
    const char* Kby = (const char*)(K + (size_t)bh * 131072);
    const char* Vby = (const char*)(Vt + (size_t)bh * 131072);
    const u16* Qb = Q + (size_t)bh * 131072;
    const int bb = bh >> 4, hh = bh & 15;
    const unsigned ck = (unsigned)(((l & 7) ^ (l >> 3)) << 4);
    const unsigned rd_swz = (unsigned)((q & 7) << 4);

    const int q0w = p * 128 + w * 32;
    const int qg = q0w + q;
    const int NT = 2 * p + 2;                 // block tile count
    const int ntw = ((q0w + 31) >> 6) + 1;    // this wave's tile count

    bf16x8 qf[4];
#pragma unroll
    for (int ks = 0; ks < 4; ++ks)
        qf[ks] = as_bf16x8(*(const u32x4*)(Qb + (size_t)(q0w + q) * 64 + ks * 16 + hi * 8));

    f32x16 o0, o1;
#pragma unroll
    for (int r = 0; r < 16; ++r) { o0[r] = 0.f; o1[r] = 0.f; }
    float lacc = 0.f;                  // lane-local unnormalized partial sum

    auto STAGE = [&](int it) {
        const int kv0 = it << 6;
        char* base = lds + (it & 1) * 16384;
#pragma unroll
        for (int j = 0; j < 2; ++j) {
            const int r = w * 16 + j * 8 + (l >> 3);
            gload_lds16(Kby + (size_t)(kv0 + r) * 128 + ck,
                        base + w * 2048 + j * 1024);
            gload_lds16(Vby + (size_t)r * 4096 + (size_t)kv0 * 2 + ck,
                        base + 8192 + w * 2048 + j * 1024);
        }
    };

    STAGE(0);
#pragma unroll 1
    for (int it = 0; it < NT; ++it) {
        asm volatile("s_waitcnt vmcnt(0)" ::: "memory");   // stage(it) landed
        ring_barrier();                 // prev readers of buf[(it+1)&1] done
        if (it + 1 < NT) STAGE(it + 1);
        if (it < ntw) {
            const int kv0 = it << 6;
            const char* Kl = lds + (it & 1) * 16384;
            const char* Vl = Kl + 8192;
            // ---- V frags from LDS (swizzled), issued early ----
            u32x4 vf[8];
#pragma unroll
            for (int kvb = 0; kvb < 2; ++kvb)
#pragma unroll
                for (int s = 0; s < 2; ++s)
#pragma unroll
                    for (int db = 0; db < 2; ++db)
                        vf[kvb * 4 + s * 2 + db] = *(const u32x4*)(
                            Vl + (unsigned)((db * 32 + q) * 128) +
                            ((unsigned)(kvb * 64 + s * 32 + hi * 16) ^ rd_swz));
            // ---- QK^T (swapped) from LDS K; Q pre-scaled (log2 units) ----
            f32x16 s0, s1;
#pragma unroll
            for (int r = 0; r < 16; ++r) { s0[r] = 0.f; s1[r] = 0.f; }
            __builtin_amdgcn_s_setprio(1);
#pragma unroll
            for (int ks = 0; ks < 4; ++ks) {
                const unsigned co = (unsigned)(ks * 32 + hi * 16) ^ rd_swz;
                bf16x8 kf0 = as_bf16x8(*(const u32x4*)(Kl + (unsigned)(q * 128) + co));
                s0 = __builtin_amdgcn_mfma_f32_32x32x16_bf16(kf0, qf[ks], s0, 0, 0, 0);
                bf16x8 kf1 = as_bf16x8(*(const u32x4*)(Kl + (unsigned)((32 + q) * 128) + co));
                s1 = __builtin_amdgcn_mfma_f32_32x32x16_bf16(kf1, qf[ks], s1, 0, 0, 0);
            }
            __builtin_amdgcn_s_setprio(0);
            // ---- causal mask (near-diagonal tiles only) ----
            if (kv0 + 63 > q0w) {
#pragma unroll
                for (int r = 0; r < 16; ++r) {
                    const int roff = (r & 3) + 8 * (r >> 2) + hi * 4;
                    if (kv0 + roff > qg) s0[r] = -1.0e30f;
                    if (kv0 + 32 + roff > qg) s1[r] = -1.0e30f;
                }
            }
            // ---- static softmax: p = exp2(s); lane-local accumulate ----
            float sm[8];
#pragma unroll
            for (int j = 0; j < 8; ++j) {
                s0[2 * j]     = exp2f(s0[2 * j]);
                s0[2 * j + 1] = exp2f(s0[2 * j + 1]);
                s1[2 * j]     = exp2f(s1[2 * j]);
                s1[2 * j + 1] = exp2f(s1[2 * j + 1]);
                sm[j] = (s0[2 * j] + s0[2 * j + 1]) + (s1[2 * j] + s1[2 * j + 1]);
            }
            lacc += ((sm[0] + sm[1]) + (sm[2] + sm[3])) +
                    ((sm[4] + sm[5]) + (sm[6] + sm[7]));
            // ---- P -> A-frags (cvt_pk + permlane32_swap) + PV ----
#pragma unroll
            for (int kvb = 0; kvb < 2; ++kvb) {
                unsigned wd[8];
#pragma unroll
                for (int j = 0; j < 8; ++j) {
                    const float plo = kvb ? s1[2 * j] : s0[2 * j];
                    const float phi = kvb ? s1[2 * j + 1] : s0[2 * j + 1];
                    wd[j] = cvtpk(plo, phi);
                }
                u32x2 r0 = __builtin_amdgcn_permlane32_swap(wd[0], wd[2], false, false);
                u32x2 r1 = __builtin_amdgcn_permlane32_swap(wd[1], wd[3], false, false);
                u32x2 r2 = __builtin_amdgcn_permlane32_swap(wd[4], wd[6], false, false);
                u32x2 r3 = __builtin_amdgcn_permlane32_swap(wd[5], wd[7], false, false);
                u32x4 fa, fb;
                fa[0] = r0[0]; fa[1] = r1[0]; fa[2] = r0[1]; fa[3] = r1[1];
                fb[0] = r2[0]; fb[1] = r3[0]; fb[2] = r2[1]; fb[3] = r3[1];
                const bf16x8 pa = as_bf16x8(fa), pb = as_bf16x8(fb);
                __builtin_amdgcn_s_setprio(1);
                o0 = __builtin_amdgcn_mfma_f32_32x32x16_bf16(pa, as_bf16x8(vf[kvb * 4 + 0]), o0, 0, 0, 0);
                o1 = __builtin_amdgcn_mfma_f32_32x32x16_bf16(pa, as_bf16x8(vf[kvb * 4 + 1]), o1, 0, 0, 0);
                o0 = __builtin_amdgcn_mfma_f32_32x32x16_bf16(pb, as_bf16x8(vf[kvb * 4 + 2]), o0, 0, 0, 0);
                o1 = __builtin_amdgcn_mfma_f32_32x32x16_bf16(pb, as_bf16x8(vf[kvb * 4 + 3]), o1, 0, 0, 0);
                __builtin_amdgcn_s_setprio(0);
            }
        }
    }
    // ---- epilogue: single cross-half reduce for lsum, then normalize ----
    float lsum;
    {
        u32x2 rr = __builtin_amdgcn_permlane32_swap(
            __float_as_uint(lacc), __float_as_uint(lacc), false, false);
        lsum = lacc + __uint_as_float(hi ? rr[0] : rr[1]);
    }
    const float linv = 1.f / lsum;
#pragma unroll
    for (int r = 0; r < 16; ++r) {
        const int roff = (r & 3) + 8 * (r >> 2) + hi * 4;
        const float invq = __shfl(linv, roff);
        const size_t base = ((size_t)(bb * 2048 + q0w + roff)) * 1024 + hh * 64 + q;
        Y[base] = f2bf(o0[r] * invq);
        Y[base + 32] = f2bf(o1[r] * invq);
    }
}

// ---------------------------------------------------------------------------
extern "C" void kernel_launch(void* const* d_in, const int* in_sizes, int n_in,
                              void* d_out, int out_size, void* d_ws, size_t ws_size,
                              hipStream_t stream) {
    const float* x = (const float*)d_in[0];
    const float* Wqkv = (const float*)d_in[1];
    const float* bqkv = (const float*)d_in[2];
    const float* Wproj = (const float*)d_in[3];
    const float* bproj = (const float*)d_in[4];
    float* out = (float*)d_out;
    char* ws = (char*)d_ws;

    u16* Wtq = (u16*)(ws + 0);            // 3072x1024 bf16
    u16* Wtp = (u16*)(ws + 6291456);      // 1024x1024 bf16
    u16* Qb  = (u16*)(ws + 8388608);      // [B,H,T,64] bf16 x3 (Q,K,V slot)
    u16* Yb  = (u16*)(ws + 41943040);     // attn output
    u16* Vtb = (u16*)(ws + 58720256);     // [B,H,64,T] bf16
    u16* Xb  = (u16*)(ws + 75497472);     // x in bf16

    xcast<<<4096, 256, 0, stream>>>(x, Xb);
    tcast2<<<dim3(16, 64), 256, 0, stream>>>(Wqkv, Wproj, Wtq, Wtp);
    gemm_kernel<0><<<dim3(64, 24), 256, 0, stream>>>(
        Xb, Wtq, bqkv, (void*)Qb, Vtb, 8192, 3072, 1024);
    attn_kernel<<<dim3(16, 64), 256, 0, stream>>>(
        Qb, Qb + 8388608, Vtb, Yb);
    gemm_kernel<1><<<dim3(64, 8), 256, 0, stream>>>(
        Yb, Wtp, bproj, (void*)out, nullptr, 8192, 1024, 1024);
}